// Round 9
// baseline (259.974 us; speedup 1.0000x reference)
//
#include <hip/hip_runtime.h>
#include <math.h>

#define BB 4
#define CC 256
#define NN 4096

using half8 = __attribute__((ext_vector_type(8))) _Float16;
using f32x4 = __attribute__((ext_vector_type(4))) float;

__device__ __forceinline__ unsigned short f2h(float f) {
  _Float16 h = (_Float16)f;   // RNE
  return __builtin_bit_cast(unsigned short, h);
}

// async global->LDS DMA, 16B per lane; LDS dest = wave-uniform base + lane*16
#define ASYNC16(g, l)                                                        \
  __builtin_amdgcn_global_load_lds(                                          \
      (const __attribute__((address_space(1))) unsigned int*)(g),            \
      (__attribute__((address_space(3))) unsigned int*)(l), 16, 0, 0)

// XOR bank swizzle at 16B-chunk granularity (applied on the GLOBAL source
// address at DMA time; LDS layout is linear in swizzled-chunk index)
__device__ __forceinline__ int row512_off(int r, int chunk) {  // rows of 512B (qa,kt), short idx
  return r * 256 + (((chunk & 24) | ((chunk ^ r) & 7)) << 3);
}
__device__ __forceinline__ int vt_off(int r, int chunk) {      // vt: 256 rows x 128B, short idx
  return r * 64 + (((chunk ^ r) & 7) << 3);
}

// ---------------- transpose: x (B,C,N) f32 -> Xt (B,N,C) fp16 ----------------
__global__ __launch_bounds__(256) void k_transpose(const float* __restrict__ x,
                                                   unsigned short* __restrict__ Xt) {
  __shared__ float tile[64][65];
  int b = blockIdx.z, c0 = blockIdx.y * 64, n0 = blockIdx.x * 64;
  int t = threadIdx.x;
  const float* xp = x + ((size_t)b * CC + c0) * NN + n0;
#pragma unroll
  for (int p = 0; p < 4; ++p) {
    int c = p * 16 + (t >> 4);
    int j = (t & 15) * 4;
    float4 v = *(const float4*)(xp + (size_t)c * NN + j);
    tile[c][j] = v.x; tile[c][j + 1] = v.y; tile[c][j + 2] = v.z; tile[c][j + 3] = v.w;
  }
  __syncthreads();
  unsigned short* xtp = Xt + ((size_t)b * NN + n0) * CC + c0;
#pragma unroll
  for (int p = 0; p < 2; ++p) {
    int n = p * 32 + (t >> 3);
    int cb = (t & 7) * 8;
    union { unsigned short u[8]; uint4 v; } tmp;
#pragma unroll
    for (int i = 0; i < 8; ++i) tmp.u[i] = f2h(tile[cb + i][n]);
    *(uint4*)(xtp + (size_t)n * CC + cb) = tmp.v;
  }
}

// ---------------- projections ----------------
__global__ __launch_bounds__(256, 1) void k_proj(const unsigned short* __restrict__ Xt,
    const float* __restrict__ Wq, const float* __restrict__ bq,
    const float* __restrict__ Wk, const float* __restrict__ bk,
    const float* __restrict__ Wv, const float* __restrict__ bv,
    unsigned short* __restrict__ Q, unsigned short* __restrict__ K,
    unsigned short* __restrict__ V) {
  __shared__ union {
    struct { unsigned short xa[128][72]; unsigned short wb[256][72]; } s;
    unsigned short qo[128][264];
    unsigned short vo[256][136];
  } u;
  int proj = blockIdx.z;
  const float* W    = proj == 0 ? Wq : (proj == 1 ? Wk : Wv);
  const float* bias = proj == 0 ? bq : (proj == 1 ? bk : bv);
  int b = blockIdx.y, n0 = blockIdx.x * 128;
  int t = threadIdx.x, w = t >> 6, lane = t & 63, l15 = lane & 15, quad = lane >> 4;

  f32x4 z = {0.f, 0.f, 0.f, 0.f};
  f32x4 acc[2][16];
#pragma unroll
  for (int i = 0; i < 2; ++i)
#pragma unroll
    for (int j = 0; j < 16; ++j) acc[i][j] = z;

  for (int ks = 0; ks < 4; ++ks) {
    __syncthreads();
#pragma unroll
    for (int p = 0; p < 4; ++p) {
      int r = p * 32 + (t >> 3);
      *(uint4*)&u.s.xa[r][(t & 7) * 8] =
        *(const uint4*)(Xt + ((size_t)b * NN + n0 + r) * CC + ks * 64 + (t & 7) * 8);
    }
#pragma unroll
    for (int p = 0; p < 16; ++p) {
      int r = p * 16 + (t >> 4);
      float4 wv = *(const float4*)(W + (size_t)r * CC + ks * 64 + (t & 15) * 4);
      ushort4 pk;
      pk.x = f2h(wv.x); pk.y = f2h(wv.y); pk.z = f2h(wv.z); pk.w = f2h(wv.w);
      *(ushort4*)&u.s.wb[r][(t & 15) * 4] = pk;
    }
    __syncthreads();
#pragma unroll
    for (int kc = 0; kc < 2; ++kc) {
      half8 af[2];
#pragma unroll
      for (int nt = 0; nt < 2; ++nt)
        af[nt] = *(const half8*)&u.s.xa[w * 32 + nt * 16 + l15][kc * 32 + quad * 8];
#pragma unroll
      for (int ct = 0; ct < 16; ++ct) {
        half8 bf = *(const half8*)&u.s.wb[ct * 16 + l15][kc * 32 + quad * 8];
        acc[0][ct] = __builtin_amdgcn_mfma_f32_16x16x32_f16(af[0], bf, acc[0][ct], 0, 0, 0);
        acc[1][ct] = __builtin_amdgcn_mfma_f32_16x16x32_f16(af[1], bf, acc[1][ct], 0, 0, 0);
      }
    }
  }
#pragma unroll
  for (int ct = 0; ct < 16; ++ct) {
    float bv_ = bias[ct * 16 + l15];
#pragma unroll
    for (int nt = 0; nt < 2; ++nt)
#pragma unroll
      for (int r = 0; r < 4; ++r) acc[nt][ct][r] += bv_;
  }
  __syncthreads();
  if (proj < 2) {
#pragma unroll
    for (int nt = 0; nt < 2; ++nt)
#pragma unroll
      for (int ct = 0; ct < 16; ++ct)
#pragma unroll
        for (int r = 0; r < 4; ++r)
          u.qo[w * 32 + nt * 16 + quad * 4 + r][ct * 16 + l15] = f2h(acc[nt][ct][r]);
    __syncthreads();
    unsigned short* out = (proj == 0 ? Q : K) + ((size_t)b * NN + n0) * CC;
#pragma unroll
    for (int p = 0; p < 16; ++p) {
      int f = p * 4096 + t * 16;
      int n = f >> 9, ob = f & 511;
      *(uint4*)((char*)out + (size_t)n * 512 + ob) =
        *(const uint4*)((const char*)&u.qo[n][0] + ob);
    }
  } else {
#pragma unroll
    for (int nt = 0; nt < 2; ++nt)
#pragma unroll
      for (int ct = 0; ct < 16; ++ct)
#pragma unroll
        for (int r = 0; r < 4; ++r)
          u.vo[ct * 16 + l15][w * 32 + nt * 16 + quad * 4 + r] = f2h(acc[nt][ct][r]);
    __syncthreads();
    unsigned short* out = V + (size_t)b * CC * NN + n0;
#pragma unroll
    for (int p = 0; p < 16; ++p) {
      int o = p * 16 + (t >> 4);
      *(uint4*)((char*)out + (size_t)o * NN * 2 + (t & 15) * 16) =
        *(const uint4*)&u.vo[o][(t & 15) * 8];
    }
  }
}

// ---------------- flash attention ----------------
// 256 threads / 4 waves / 32 q-rows per wave (128 q per block).
// r8 counters showed LDS read-issue is the ceiling (66 b128/wave/iter x 8
// waves ~ 9400 cyc/iter); traffic scales with waves x (K+V tile bytes), so
// doubling q-per-wave halves LDS reads per unit work. o_acc (128 VGPR) +
// state needs the 256-VGPR budget of a 256-thread block (512-thd caps at
// 128, r5/6); Q therefore lives in LDS (qa, 64 KB) instead of registers.
// K/V single-buffered with phase-interleaved DMA: V(it) lands during the
// S-phase (drained at mid-barrier), K(it+1) lands during softmax+PV
// (drained at end-barrier) — no exposed DMA drain.
__global__ __launch_bounds__(256, 1) void k_flash(const unsigned short* __restrict__ Q,
    const unsigned short* __restrict__ K, const unsigned short* __restrict__ V,
    float* __restrict__ out, float* __restrict__ opart, float* __restrict__ ml,
    int n_splits) {
  __shared__ unsigned short qa[32768];  // 64KB: 128 q x 256 c (row512 swizzle)
  __shared__ unsigned short kt[16384];  // 32KB: 64 keys x 256 c (row512 swizzle)
  __shared__ unsigned short vt[16384];  // 32KB: 256 c x 64 keys (vt swizzle)
  __shared__ unsigned short pt[8192];   // 16KB: 4 waves x 32 q x 64 k
  int b = blockIdx.y, q0 = blockIdx.x * 128, split = blockIdx.z;
  int nper = 64 / n_splits;
  int t = threadIdx.x, w = t >> 6, lane = t & 63, l15 = lane & 15, quad = lane >> 4;

  f32x4 z = {0.f, 0.f, 0.f, 0.f};
  f32x4 o_acc[2][16];
#pragma unroll
  for (int mt = 0; mt < 2; ++mt)
#pragma unroll
    for (int i = 0; i < 16; ++i) o_acc[mt][i] = z;
  float m_i[2][4], lp_[2][4];
#pragma unroll
  for (int mt = 0; mt < 2; ++mt)
#pragma unroll
    for (int r = 0; r < 4; ++r) { m_i[mt][r] = -INFINITY; lp_[mt][r] = 0.f; }

  int it_beg = split * nper, it_end = it_beg + nper;

  auto dma_k = [&](int it) {
    const char* kb = (const char*)(K + ((size_t)b * NN + it * 64) * CC);
#pragma unroll
    for (int p = 0; p < 8; ++p) {
      int c = p * 256 + t;
      int r = c >> 5, lo = c & 31;
      int chunk = (lo & 24) | ((lo ^ r) & 7);
      ASYNC16(kb + r * 512 + chunk * 16, &kt[(p * 256 + (w << 6)) * 8]);
    }
  };
  auto dma_v = [&](int it) {
    const char* vb = (const char*)(V + (size_t)b * CC * NN + it * 64);
#pragma unroll
    for (int p = 0; p < 8; ++p) {
      int c = p * 256 + t;
      int r = c >> 3;
      int chunk = (c ^ r) & 7;
      ASYNC16(vb + (size_t)r * 8192 + chunk * 16, &vt[(p * 256 + (w << 6)) * 8]);
    }
  };

  // prologue: Q tile (once) + first K tile
  {
    const char* qb = (const char*)(Q + ((size_t)b * NN + q0) * CC);
#pragma unroll
    for (int p = 0; p < 16; ++p) {
      int c = p * 256 + t;
      int r = c >> 5, lo = c & 31;
      int chunk = (lo & 24) | ((lo ^ r) & 7);
      ASYNC16(qb + r * 512 + chunk * 16, &qa[(p * 256 + (w << 6)) * 8]);
    }
    dma_k(it_beg);
  }
  __syncthreads();

  for (int it = it_beg; it < it_end; ++it) {
    dma_v(it);   // lands during S-phase, drained at mid-barrier

    // S = Q K^T : 32 q x 64 keys per wave
    f32x4 sa[2][4];
#pragma unroll
    for (int mt = 0; mt < 2; ++mt)
#pragma unroll
      for (int j = 0; j < 4; ++j) sa[mt][j] = z;
#pragma unroll
    for (int kk = 0; kk < 8; ++kk) {
      half8 af[2];
#pragma unroll
      for (int mt = 0; mt < 2; ++mt)
        af[mt] = *(const half8*)&qa[row512_off(w * 32 + mt * 16 + l15, kk * 4 + quad)];
#pragma unroll
      for (int j = 0; j < 4; ++j) {
        half8 bf = *(const half8*)&kt[row512_off(j * 16 + l15, kk * 4 + quad)];
#pragma unroll
        for (int mt = 0; mt < 2; ++mt)
          sa[mt][j] = __builtin_amdgcn_mfma_f32_16x16x32_f16(af[mt], bf, sa[mt][j], 0, 0, 0);
      }
    }
    __syncthreads();             // mid-barrier: drains V DMA; kt now free
    if (it + 1 < it_end) dma_k(it + 1);   // lands during softmax+PV

    // online softmax (rows: mt*16 + quad*4 + r within the wave's 32 q)
#pragma unroll
    for (int mt = 0; mt < 2; ++mt) {
      float mtx[4];
#pragma unroll
      for (int r = 0; r < 4; ++r)
        mtx[r] = fmaxf(fmaxf(sa[mt][0][r], sa[mt][1][r]), fmaxf(sa[mt][2][r], sa[mt][3][r]));
#pragma unroll
      for (int off = 1; off < 16; off <<= 1)
#pragma unroll
        for (int r = 0; r < 4; ++r)
          mtx[r] = fmaxf(mtx[r], __shfl_xor(mtx[r], off, 64));
      float alpha[4];
#pragma unroll
      for (int r = 0; r < 4; ++r) {
        float mn = fmaxf(m_i[mt][r], mtx[r]);
        alpha[r] = __expf(m_i[mt][r] - mn);
        m_i[mt][r] = mn;
      }
#pragma unroll
      for (int r = 0; r < 4; ++r) {
        float ls = 0.f;
#pragma unroll
        for (int j = 0; j < 4; ++j) {
          float p = __expf(sa[mt][j][r] - m_i[mt][r]);
          sa[mt][j][r] = p;
          ls += p;
        }
        lp_[mt][r] = lp_[mt][r] * alpha[r] + ls;
      }
#pragma unroll
      for (int ct = 0; ct < 16; ++ct)
#pragma unroll
        for (int r = 0; r < 4; ++r) o_acc[mt][ct][r] *= alpha[r];
      // P (C/D layout) -> per-wave LDS scratch (A-operand layout)
#pragma unroll
      for (int j = 0; j < 4; ++j)
#pragma unroll
        for (int r = 0; r < 4; ++r) {
          int row = mt * 16 + quad * 4 + r;           // wave-local q (0..31)
          int chunk = 2 * j + (l15 >> 3);             // key 16B-chunk (0..7)
          pt[w * 2048 + row * 64 + (((chunk ^ row) & 7) << 3) + (l15 & 7)] = f2h(sa[mt][j][r]);
        }
    }
    // O += P @ V^T
#pragma unroll
    for (int kk2 = 0; kk2 < 2; ++kk2) {
      half8 af[2];
#pragma unroll
      for (int mt = 0; mt < 2; ++mt) {
        int row = mt * 16 + l15;
        af[mt] = *(const half8*)&pt[w * 2048 + row * 64 + ((((kk2 * 4 + quad) ^ row) & 7) << 3)];
      }
#pragma unroll
      for (int ct = 0; ct < 16; ++ct) {
        half8 bf = *(const half8*)&vt[vt_off(ct * 16 + l15, kk2 * 4 + quad)];
#pragma unroll
        for (int mt = 0; mt < 2; ++mt)
          o_acc[mt][ct] = __builtin_amdgcn_mfma_f32_16x16x32_f16(af[mt], bf, o_acc[mt][ct], 0, 0, 0);
      }
    }
    __syncthreads();             // end-barrier: drains K DMA; vt now free
  }

  // final 16-lane sum reduction of l partials
#pragma unroll
  for (int off = 1; off < 16; off <<= 1)
#pragma unroll
    for (int mt = 0; mt < 2; ++mt)
#pragma unroll
      for (int r = 0; r < 4; ++r)
        lp_[mt][r] += __shfl_xor(lp_[mt][r], off, 64);

  float sc[2][4];
#pragma unroll
  for (int mt = 0; mt < 2; ++mt)
#pragma unroll
    for (int r = 0; r < 4; ++r)
      sc[mt][r] = (n_splits == 1) ? 1.f / lp_[mt][r] : 1.f;

  // epilogue: stage O via qa reinterpreted as od[32][132] f32, 8 passes of 32 c
  float* od = (float*)qa;
  float* ob = (n_splits == 1 ? out : opart + (size_t)split * BB * CC * NN)
              + (size_t)b * CC * NN + q0;
#pragma unroll
  for (int pp = 0; pp < 8; ++pp) {
    __syncthreads();
#pragma unroll
    for (int cp = 0; cp < 2; ++cp) {
      int ct = pp * 2 + cp;
#pragma unroll
      for (int mt = 0; mt < 2; ++mt)
#pragma unroll
        for (int r = 0; r < 4; ++r)
          od[(cp * 16 + l15) * 132 + w * 32 + mt * 16 + quad * 4 + r] =
              o_acc[mt][ct][r] * sc[mt][r];
    }
    __syncthreads();
#pragma unroll
    for (int p2 = 0; p2 < 4; ++p2) {
      int row = p2 * 8 + (t >> 5);
      *(float4*)(ob + (size_t)(pp * 32 + row) * NN + (t & 31) * 4) =
        *(const float4*)&od[row * 132 + (t & 31) * 4];
    }
  }
  if (n_splits != 1 && l15 == 0) {
    float* mp = ml + ((size_t)(split * 2 + 0) * BB + b) * NN + q0 + w * 32 + quad * 4;
    float* lq = ml + ((size_t)(split * 2 + 1) * BB + b) * NN + q0 + w * 32 + quad * 4;
#pragma unroll
    for (int mt = 0; mt < 2; ++mt)
#pragma unroll
      for (int r = 0; r < 4; ++r) { mp[mt * 16 + r] = m_i[mt][r]; lq[mt * 16 + r] = lp_[mt][r]; }
  }
}

// ---------------- merge of 2 key-splits ----------------
__global__ __launch_bounds__(256) void k_merge(const float* __restrict__ opart,
    const float* __restrict__ ml, float* __restrict__ out) {
  size_t i = ((size_t)blockIdx.x * 256 + threadIdx.x) * 4;
  int n = (int)(i & (NN - 1));
  int b = (int)(i >> 20);   // i / (CC*NN)
  float4 m1 = *(const float4*)(ml + (size_t)(0 * BB + b) * NN + n);
  float4 l1 = *(const float4*)(ml + (size_t)(1 * BB + b) * NN + n);
  float4 m2 = *(const float4*)(ml + (size_t)(2 * BB + b) * NN + n);
  float4 l2 = *(const float4*)(ml + (size_t)(3 * BB + b) * NN + n);
  float4 o1 = *(const float4*)(opart + i);
  float4 o2 = *(const float4*)(opart + (size_t)BB * CC * NN + i);
  float4 o;
#define MERGE1(f) { \
    float mm = fmaxf(m1.f, m2.f); \
    float e1 = __expf(m1.f - mm), e2 = __expf(m2.f - mm); \
    o.f = (e1 * o1.f + e2 * o2.f) / (e1 * l1.f + e2 * l2.f); }
  MERGE1(x) MERGE1(y) MERGE1(z) MERGE1(w)
#undef MERGE1
  *(float4*)(out + i) = o;
}

extern "C" void kernel_launch(void* const* d_in, const int* in_sizes, int n_in,
                              void* d_out, int out_size, void* d_ws, size_t ws_size,
                              hipStream_t stream) {
  const float* x  = (const float*)d_in[0];
  const float* Wq = (const float*)d_in[1];
  const float* bq = (const float*)d_in[2];
  const float* Wk = (const float*)d_in[3];
  const float* bk = (const float*)d_in[4];
  const float* Wv = (const float*)d_in[5];
  const float* bv = (const float*)d_in[6];
  float* out = (float*)d_out;
  char* ws = (char*)d_ws;
  unsigned short* Xt = (unsigned short*)(ws);
  unsigned short* Qb = (unsigned short*)(ws + (size_t)8  * 1024 * 1024);
  unsigned short* Kb = (unsigned short*)(ws + (size_t)16 * 1024 * 1024);
  unsigned short* Vb = (unsigned short*)(ws + (size_t)24 * 1024 * 1024);
  float* Opart = (float*)(ws + (size_t)32 * 1024 * 1024);  // 2 x 16 MB
  float* Ml    = (float*)(ws + (size_t)64 * 1024 * 1024);  // 4 x 64 KB

  k_transpose<<<dim3(64, 4, 4), 256, 0, stream>>>(x, Xt);
  k_proj<<<dim3(32, 4, 3), 256, 0, stream>>>(Xt, Wq, bq, Wk, bk, Wv, bv, Qb, Kb, Vb);

  bool split2 = ws_size >= (size_t)68 * 1024 * 1024;
  if (split2) {
    k_flash<<<dim3(32, 4, 2), 256, 0, stream>>>(Qb, Kb, Vb, out, Opart, Ml, 2);
    k_merge<<<dim3(4096), 256, 0, stream>>>(Opart, Ml, out);
  } else {
    k_flash<<<dim3(32, 4, 1), 256, 0, stream>>>(Qb, Kb, Vb, out, Opart, Ml, 1);
  }
}

// Round 10
// 230.648 us; speedup vs baseline: 1.1271x; 1.1271x over previous
//
#include <hip/hip_runtime.h>
#include <math.h>

#define BB 4
#define CC 256
#define NN 4096

using half8 = __attribute__((ext_vector_type(8))) _Float16;
using f32x4 = __attribute__((ext_vector_type(4))) float;

__device__ __forceinline__ unsigned short f2h(float f) {
  _Float16 h = (_Float16)f;   // RNE
  return __builtin_bit_cast(unsigned short, h);
}
__device__ __forceinline__ float h2f(unsigned short u) {
  return (float)__builtin_bit_cast(_Float16, u);
}

// async global->LDS DMA, 16B per lane; LDS dest = wave-uniform base + lane*16
#define ASYNC16(g, l)                                                        \
  __builtin_amdgcn_global_load_lds(                                          \
      (const __attribute__((address_space(1))) unsigned int*)(g),            \
      (__attribute__((address_space(3))) unsigned int*)(l), 16, 0, 0)

// XOR bank swizzle at 16B-chunk granularity. Inverse swizzle is applied on
// the GLOBAL source address at DMA time (involution), LDS is chunk-linear.
__device__ __forceinline__ int row512_off(int r, int chunk) {  // rows of 512B
  return r * 256 + (((chunk & 24) | ((chunk ^ r) & 7)) << 3);
}
__device__ __forceinline__ int vt_off(int r, int chunk) {      // rows of 128B
  return r * 64 + (((chunk ^ r) & 7) << 3);
}

// ---------------- transpose: x (B,C,N) f32 -> Xt (B,N,C) fp16 ----------------
__global__ __launch_bounds__(256) void k_transpose(const float* __restrict__ x,
                                                   unsigned short* __restrict__ Xt) {
  __shared__ float tile[64][65];
  int b = blockIdx.z, c0 = blockIdx.y * 64, n0 = blockIdx.x * 64;
  int t = threadIdx.x;
  const float* xp = x + ((size_t)b * CC + c0) * NN + n0;
#pragma unroll
  for (int p = 0; p < 4; ++p) {
    int c = p * 16 + (t >> 4);
    int j = (t & 15) * 4;
    float4 v = *(const float4*)(xp + (size_t)c * NN + j);
    tile[c][j] = v.x; tile[c][j + 1] = v.y; tile[c][j + 2] = v.z; tile[c][j + 3] = v.w;
  }
  __syncthreads();
  unsigned short* xtp = Xt + ((size_t)b * NN + n0) * CC + c0;
#pragma unroll
  for (int p = 0; p < 2; ++p) {
    int n = p * 32 + (t >> 3);
    int cb = (t & 7) * 8;
    union { unsigned short u[8]; uint4 v; } tmp;
#pragma unroll
    for (int i = 0; i < 8; ++i) tmp.u[i] = f2h(tile[cb + i][n]);
    *(uint4*)(xtp + (size_t)n * CC + cb) = tmp.v;
  }
}

// ---------------- W cast: 3x(256x256) f32 -> fp16 ----------------
__global__ __launch_bounds__(256) void k_wcast(const float* __restrict__ Wq,
    const float* __restrict__ Wk, const float* __restrict__ Wv,
    unsigned short* __restrict__ Wh) {
  const float* W = blockIdx.y == 0 ? Wq : (blockIdx.y == 1 ? Wk : Wv);
  int idx = blockIdx.x * 1024 + threadIdx.x * 4;
  float4 v = *(const float4*)(W + idx);
  union { unsigned short u[4]; uint2 v2; } pk;
  pk.u[0] = f2h(v.x); pk.u[1] = f2h(v.y); pk.u[2] = f2h(v.z); pk.u[3] = f2h(v.w);
  *(uint2*)(Wh + blockIdx.y * 65536 + idx) = pk.v2;
}

// ---------------- projections (512-thd, W resident in LDS, DMA staging) ------
__global__ __launch_bounds__(512) void k_proj(const unsigned short* __restrict__ Xt,
    const unsigned short* __restrict__ Wh,
    const float* __restrict__ bq, const float* __restrict__ bk,
    const float* __restrict__ bv,
    unsigned short* __restrict__ Q, unsigned short* __restrict__ K,
    unsigned short* __restrict__ V) {
  __shared__ unsigned short ps[73728];   // wh 65536 | xa 8192 (shorts) = 144 KB
  unsigned short* wh = ps;
  unsigned short* xa = ps + 65536;
  int proj = blockIdx.z, b = blockIdx.y, n0 = blockIdx.x * 128;
  int t = threadIdx.x, w = t >> 6, lane = t & 63, l15 = lane & 15, quad = lane >> 4;
  const unsigned short* Wp = Wh + proj * 65536;
  const float* bias = proj == 0 ? bq : (proj == 1 ? bk : bv);

  // stage full W (256x256 fp16 = 128 KB) once via DMA
#pragma unroll
  for (int p = 0; p < 16; ++p) {
    int c = p * 512 + t;
    int r = c >> 5, lo = c & 31;
    int ch = (lo & 24) | ((lo ^ r) & 7);
    ASYNC16((const char*)Wp + r * 512 + ch * 16, &wh[(p * 512 + (w << 6)) * 8]);
  }

  f32x4 z = {0.f, 0.f, 0.f, 0.f};
  f32x4 acc[16];
#pragma unroll
  for (int i = 0; i < 16; ++i) acc[i] = z;

  for (int ks = 0; ks < 4; ++ks) {
    if (ks) __syncthreads();       // all waves done reading xa(ks-1)
#pragma unroll
    for (int p = 0; p < 2; ++p) {  // stage Xt 128n x 64c fp16 tile
      int c = p * 512 + t;
      int r = c >> 3;
      int ch = (c ^ r) & 7;
      ASYNC16((const char*)(Xt + ((size_t)b * NN + n0 + r) * CC + ks * 64) + ch * 16,
              &xa[(p * 512 + (w << 6)) * 8]);
    }
    __syncthreads();               // drain (W included on first pass)
#pragma unroll
    for (int kc = 0; kc < 2; ++kc) {
      half8 af = *(const half8*)&xa[vt_off(w * 16 + l15, kc * 4 + quad)];
#pragma unroll
      for (int ct = 0; ct < 16; ++ct) {
        half8 bf = *(const half8*)&wh[row512_off(ct * 16 + l15, ks * 8 + kc * 4 + quad)];
        acc[ct] = __builtin_amdgcn_mfma_f32_16x16x32_f16(af, bf, acc[ct], 0, 0, 0);
      }
    }
  }
#pragma unroll
  for (int ct = 0; ct < 16; ++ct) {
    float bv_ = bias[ct * 16 + l15];
#pragma unroll
    for (int r = 0; r < 4; ++r) acc[ct][r] += bv_;
  }
  __syncthreads();   // wh/xa dead; reuse ps as epilogue staging
  if (proj < 2) {
    unsigned short (*qo)[264] = (unsigned short(*)[264])ps;  // 128 x 264 shorts
#pragma unroll
    for (int ct = 0; ct < 16; ++ct)
#pragma unroll
      for (int r = 0; r < 4; ++r)
        qo[w * 16 + quad * 4 + r][ct * 16 + l15] = f2h(acc[ct][r]);
    __syncthreads();
    unsigned short* outp = (proj == 0 ? Q : K) + ((size_t)b * NN + n0) * CC;
#pragma unroll
    for (int p = 0; p < 8; ++p) {
      int f = p * 8192 + t * 16;
      int n = f >> 9, off = f & 511;
      *(uint4*)((char*)outp + (size_t)n * 512 + off) =
        *(const uint4*)((const char*)&qo[n][0] + off);
    }
  } else {
    unsigned short (*vo)[132] = (unsigned short(*)[132])ps;  // 256 x 132 shorts
#pragma unroll
    for (int ct = 0; ct < 16; ++ct)
#pragma unroll
      for (int r = 0; r < 4; ++r)
        vo[ct * 16 + l15][w * 16 + quad * 4 + r] = f2h(acc[ct][r]);
    __syncthreads();
#pragma unroll
    for (int p = 0; p < 8; ++p) {
      int f = p * 8192 + t * 16;
      int o = f >> 8, off = f & 255;
      *(uint4*)((char*)V + (((size_t)b * CC + o) * NN + n0) * 2 + off) =
        *(const uint4*)((const char*)&vo[o][0] + off);
    }
  }
}

// ---------------- flash attention (512-thd, 72 KB LDS, key-split) ------------
// q=16/wave x 8 waves = 128 q/block. Single K/V buffer, phase-interleaved DMA:
// dma_v(it) lands during the S-phase (drained at mid-barrier), dma_k(it+1)
// lands during softmax+PV (drained at end-barrier). LDS = 72 KB so two
// 512-thd blocks (16 waves) can co-reside per CU (2x72=144 <= 160 KiB).
__global__ __launch_bounds__(512) void k_flash(const unsigned short* __restrict__ Q,
    const unsigned short* __restrict__ K, const unsigned short* __restrict__ V,
    float* __restrict__ out, unsigned short* __restrict__ opart,
    float* __restrict__ ml, int n_splits) {
  __shared__ unsigned short smem[36864];   // kt 16384 | vt 16384 | pt 4096 shorts
  unsigned short* kt = smem;
  unsigned short* vt = smem + 16384;
  unsigned short* pt = smem + 32768;
  int b = blockIdx.y, q0 = blockIdx.x * 128, split = blockIdx.z;
  int nper = 64 / n_splits;
  int t = threadIdx.x, w = t >> 6, lane = t & 63, l15 = lane & 15, quad = lane >> 4;

  // Q fragments in registers (loop-invariant): A[q=l15][c=quad*8+j]
  half8 qf[8];
  const unsigned short* qrow = Q + ((size_t)b * NN + q0 + w * 16 + l15) * CC;
#pragma unroll
  for (int k = 0; k < 8; ++k) qf[k] = *(const half8*)(qrow + k * 32 + quad * 8);

  f32x4 z = {0.f, 0.f, 0.f, 0.f};
  f32x4 o_acc[16];
#pragma unroll
  for (int i = 0; i < 16; ++i) o_acc[i] = z;
  float m_i[4], lp_[4];
#pragma unroll
  for (int r = 0; r < 4; ++r) { m_i[r] = -INFINITY; lp_[r] = 0.f; }

  int it_beg = split * nper, it_end = it_beg + nper;

  auto dma_k = [&](int it) {
    const char* kb = (const char*)(K + ((size_t)b * NN + it * 64) * CC);
#pragma unroll
    for (int p = 0; p < 4; ++p) {
      int c = p * 512 + t;
      int r = c >> 5, lo = c & 31;
      int ch = (lo & 24) | ((lo ^ r) & 7);
      ASYNC16(kb + r * 512 + ch * 16, &kt[(p * 512 + (w << 6)) * 8]);
    }
  };
  auto dma_v = [&](int it) {
    const char* vb = (const char*)(V + (size_t)b * CC * NN + it * 64);
#pragma unroll
    for (int p = 0; p < 4; ++p) {
      int c = p * 512 + t;
      int r = c >> 3;
      int ch = (c ^ r) & 7;
      ASYNC16(vb + (size_t)r * 8192 + ch * 16, &vt[(p * 512 + (w << 6)) * 8]);
    }
  };

  dma_k(it_beg);
  __syncthreads();

  for (int it = it_beg; it < it_end; ++it) {
    dma_v(it);   // lands during S-phase

    f32x4 sa[4];
#pragma unroll
    for (int j = 0; j < 4; ++j) sa[j] = z;
#pragma unroll
    for (int kk = 0; kk < 8; ++kk) {
#pragma unroll
      for (int j = 0; j < 4; ++j) {
        half8 bf = *(const half8*)&kt[row512_off(j * 16 + l15, kk * 4 + quad)];
        sa[j] = __builtin_amdgcn_mfma_f32_16x16x32_f16(qf[kk], bf, sa[j], 0, 0, 0);
      }
    }
    __syncthreads();                    // vt ready; kt free
    if (it + 1 < it_end) dma_k(it + 1); // lands during softmax+PV

    // online softmax: max butterfly; sum kept per-lane (reduced after loop)
    float mt[4];
#pragma unroll
    for (int r = 0; r < 4; ++r)
      mt[r] = fmaxf(fmaxf(sa[0][r], sa[1][r]), fmaxf(sa[2][r], sa[3][r]));
#pragma unroll
    for (int off = 1; off < 16; off <<= 1)
#pragma unroll
      for (int r = 0; r < 4; ++r)
        mt[r] = fmaxf(mt[r], __shfl_xor(mt[r], off, 64));
    float alpha[4];
#pragma unroll
    for (int r = 0; r < 4; ++r) {
      float mn = fmaxf(m_i[r], mt[r]);
      alpha[r] = __expf(m_i[r] - mn);
      m_i[r] = mn;
    }
#pragma unroll
    for (int r = 0; r < 4; ++r) {
      float ls = 0.f;
#pragma unroll
      for (int j = 0; j < 4; ++j) {
        float p = __expf(sa[j][r] - m_i[r]);
        sa[j][r] = p;
        ls += p;
      }
      lp_[r] = lp_[r] * alpha[r] + ls;
    }
#pragma unroll
    for (int ct = 0; ct < 16; ++ct)
#pragma unroll
      for (int r = 0; r < 4; ++r) o_acc[ct][r] *= alpha[r];

    // PV in two 32-key halves through per-wave pt (same-wave in-order DS)
#pragma unroll
    for (int hf = 0; hf < 2; ++hf) {
#pragma unroll
      for (int j2 = 0; j2 < 2; ++j2) {
#pragma unroll
        for (int r = 0; r < 4; ++r) {
          int row = quad * 4 + r;
          int ch = 2 * j2 + (l15 >> 3);
          pt[w * 512 + row * 32 + (((ch ^ row) & 3) << 3) + (l15 & 7)] =
              f2h(sa[hf * 2 + j2][r]);
        }
      }
      half8 af = *(const half8*)&pt[w * 512 + l15 * 32 + (((quad ^ l15) & 3) << 3)];
#pragma unroll
      for (int ct = 0; ct < 16; ++ct) {
        half8 bf = *(const half8*)&vt[vt_off(ct * 16 + l15, hf * 4 + quad)];
        o_acc[ct] = __builtin_amdgcn_mfma_f32_16x16x32_f16(af, bf, o_acc[ct], 0, 0, 0);
      }
    }
    __syncthreads();                    // kt(it+1) ready; vt free
  }

  // final 16-lane sum reduction of l partials
#pragma unroll
  for (int off = 1; off < 16; off <<= 1)
#pragma unroll
    for (int r = 0; r < 4; ++r)
      lp_[r] += __shfl_xor(lp_[r], off, 64);

  float sc[4];
#pragma unroll
  for (int r = 0; r < 4; ++r) sc[r] = (n_splits == 1) ? 1.f / lp_[r] : 1.f;

  // epilogue: od fp32 [64][132] overlay on smem, 4 quarters of 64 c
  float* od = (float*)smem;
  float* obf = out + (size_t)b * CC * NN + q0;
  unsigned short* obh = opart + ((size_t)split * BB + b) * CC * NN + q0;
#pragma unroll
  for (int qtr = 0; qtr < 4; ++qtr) {
    __syncthreads();
#pragma unroll
    for (int cp = 0; cp < 4; ++cp) {
      int ct = qtr * 4 + cp;
#pragma unroll
      for (int r = 0; r < 4; ++r)
        od[(cp * 16 + l15) * 132 + w * 16 + quad * 4 + r] = o_acc[ct][r] * sc[r];
    }
    __syncthreads();
    if (n_splits == 1) {
#pragma unroll
      for (int p2 = 0; p2 < 4; ++p2) {
        int row = p2 * 16 + (t >> 5);
        *(float4*)(obf + (size_t)(qtr * 64 + row) * NN + (t & 31) * 4) =
          *(const float4*)&od[row * 132 + (t & 31) * 4];
      }
    } else {
#pragma unroll
      for (int p2 = 0; p2 < 2; ++p2) {
        int row = p2 * 32 + (t >> 4);
        int q8 = (t & 15) * 8;
        union { unsigned short u[8]; uint4 v4; } tmp;
#pragma unroll
        for (int i2 = 0; i2 < 8; ++i2) tmp.u[i2] = f2h(od[row * 132 + q8 + i2]);
        *(uint4*)(obh + (size_t)(qtr * 64 + row) * NN + q8) = tmp.v4;
      }
    }
  }
  if (n_splits != 1 && l15 == 0) {
    size_t qi = (size_t)q0 + w * 16 + quad * 4;
    float* mp = ml + ((size_t)(split * 2 + 0) * BB + b) * NN + qi;
    float* lq = ml + ((size_t)(split * 2 + 1) * BB + b) * NN + qi;
#pragma unroll
    for (int r = 0; r < 4; ++r) { mp[r] = m_i[r]; lq[r] = lp_[r]; }
  }
}

// ---------------- merge of 4 key-splits ----------------
__global__ __launch_bounds__(256) void k_merge(const unsigned short* __restrict__ opart,
    const float* __restrict__ ml, float* __restrict__ out) {
  size_t i = ((size_t)blockIdx.x * 256 + threadIdx.x) * 4;
  int n = (int)(i & (NN - 1));
  int b = (int)(i >> 20);   // i / (CC*NN)
  float4 m[4], l[4];
  ushort4 o[4];
#pragma unroll
  for (int s = 0; s < 4; ++s) {
    m[s] = *(const float4*)(ml + ((size_t)(s * 2 + 0) * BB + b) * NN + n);
    l[s] = *(const float4*)(ml + ((size_t)(s * 2 + 1) * BB + b) * NN + n);
    o[s] = *(const ushort4*)(opart + (size_t)s * BB * CC * NN + i);
  }
  float4 res;
#define MRG(f, comp) { \
    float M = fmaxf(fmaxf(m[0].f, m[1].f), fmaxf(m[2].f, m[3].f)); \
    float num = 0.f, den = 0.f; \
    num += __expf(m[0].f - M) * h2f(o[0].comp); den += __expf(m[0].f - M) * l[0].f; \
    num += __expf(m[1].f - M) * h2f(o[1].comp); den += __expf(m[1].f - M) * l[1].f; \
    num += __expf(m[2].f - M) * h2f(o[2].comp); den += __expf(m[2].f - M) * l[2].f; \
    num += __expf(m[3].f - M) * h2f(o[3].comp); den += __expf(m[3].f - M) * l[3].f; \
    res.f = num / den; }
  MRG(x, x) MRG(y, y) MRG(z, z) MRG(w, w)
#undef MRG
  *(float4*)(out + i) = res;
}

extern "C" void kernel_launch(void* const* d_in, const int* in_sizes, int n_in,
                              void* d_out, int out_size, void* d_ws, size_t ws_size,
                              hipStream_t stream) {
  const float* x  = (const float*)d_in[0];
  const float* Wq = (const float*)d_in[1];
  const float* bq = (const float*)d_in[2];
  const float* Wk = (const float*)d_in[3];
  const float* bk = (const float*)d_in[4];
  const float* Wv = (const float*)d_in[5];
  const float* bv = (const float*)d_in[6];
  float* out = (float*)d_out;
  char* ws = (char*)d_ws;
  const size_t MB = 1024 * 1024;
  unsigned short* Qb = (unsigned short*)(ws);                 // 8 MB fp16 (B,N,C)
  unsigned short* Kb = (unsigned short*)(ws + 8 * MB);        // 8 MB fp16 (B,N,C)
  unsigned short* Vb = (unsigned short*)(ws + 16 * MB);       // 8 MB fp16 (B,C,N)
  unsigned short* Xt = (unsigned short*)(ws + 24 * MB);       // 8 MB fp16 (B,N,C)
  unsigned short* Wh = (unsigned short*)(ws + 32 * MB);       // 384 KB fp16
  float*          Ml = (float*)(ws + 33 * MB);                // 512 KB
  unsigned short* Op = (unsigned short*)(ws + 34 * MB);       // 32 MB fp16 partials

  k_wcast<<<dim3(64, 3), 256, 0, stream>>>(Wq, Wk, Wv, Wh);
  k_transpose<<<dim3(64, 4, 4), 256, 0, stream>>>(x, Xt);
  k_proj<<<dim3(32, 4, 3), 512, 0, stream>>>(Xt, Wh, bq, bk, bv, Qb, Kb, Vb);

  int ns = (ws_size >= 66 * MB) ? 4 : 1;
  k_flash<<<dim3(32, 4, ns), 512, 0, stream>>>(Qb, Kb, Vb, out, Op, Ml, ns);
  if (ns == 4) k_merge<<<dim3(4096), 256, 0, stream>>>(Op, Ml, out);
}

// Round 11
// 215.097 us; speedup vs baseline: 1.2086x; 1.0723x over previous
//
#include <hip/hip_runtime.h>
#include <math.h>

#define BB 4
#define CC 256
#define NN 4096

using half8 = __attribute__((ext_vector_type(8))) _Float16;
using f32x4 = __attribute__((ext_vector_type(4))) float;

__device__ __forceinline__ unsigned short f2h(float f) {
  _Float16 h = (_Float16)f;   // RNE
  return __builtin_bit_cast(unsigned short, h);
}
__device__ __forceinline__ float h2f(unsigned short u) {
  return (float)__builtin_bit_cast(_Float16, u);
}

// async global->LDS DMA, 16B per lane; LDS dest = wave-uniform base + lane*16
#define ASYNC16(g, l)                                                        \
  __builtin_amdgcn_global_load_lds(                                          \
      (const __attribute__((address_space(1))) unsigned int*)(g),            \
      (__attribute__((address_space(3))) unsigned int*)(l), 16, 0, 0)

// XOR bank swizzle at 16B-chunk granularity
__device__ __forceinline__ int row512_off(int r, int chunk) {  // rows of 512B
  return r * 256 + (((chunk & 24) | ((chunk ^ r) & 7)) << 3);
}
__device__ __forceinline__ int vt_off(int r, int chunk) {      // rows of 128B
  return r * 64 + (((chunk ^ r) & 7) << 3);
}

// ---------------- fused transpose + cast + projections ----------------
// Reads x (B,C,N) f32 directly; per 64-c step: stage x f32 tile in LDS,
// transpose-pack to fp16 A-layout; W cast f32->fp16 in-kernel to B-layout.
// Q[b,n,o], K[b,n,o] stored (B,N,C) fp16; V stored (B,C,N) fp16.
__global__ __launch_bounds__(512) void k_proj(const float* __restrict__ x,
    const float* __restrict__ Wq, const float* __restrict__ bq,
    const float* __restrict__ Wk, const float* __restrict__ bk,
    const float* __restrict__ Wv, const float* __restrict__ bv,
    unsigned short* __restrict__ Q, unsigned short* __restrict__ K,
    unsigned short* __restrict__ V) {
  __shared__ __align__(16) char ps[84992];
  float* xf = (float*)ps;                               // 64 x 133 f32 (34048 B)
  unsigned short* wh = (unsigned short*)(ps + 34048);   // 256 x 64 fp16 (32768 B)
  unsigned short* xa = (unsigned short*)(ps + 66816);   // 128 x 64 fp16 (16384 B)
  int proj = blockIdx.z, b = blockIdx.y, n0 = blockIdx.x * 128;
  int t = threadIdx.x, w = t >> 6, lane = t & 63, l15 = lane & 15, quad = lane >> 4;
  const float* W    = proj == 0 ? Wq : (proj == 1 ? Wk : Wv);
  const float* bias = proj == 0 ? bq : (proj == 1 ? bk : bv);

  f32x4 z = {0.f, 0.f, 0.f, 0.f};
  f32x4 acc[16];
#pragma unroll
  for (int i = 0; i < 16; ++i) acc[i] = z;

  for (int ks = 0; ks < 4; ++ks) {
    if (ks) __syncthreads();
    // x f32 tile: 64 c-rows x 128 n (coalesced rows)
#pragma unroll
    for (int p = 0; p < 4; ++p) {
      int c = p * 16 + (t >> 5), nl = (t & 31) * 4;
      float4 v = *(const float4*)(x + ((size_t)b * CC + ks * 64 + c) * NN + n0 + nl);
      float* d = xf + c * 133 + nl;
      d[0] = v.x; d[1] = v.y; d[2] = v.z; d[3] = v.w;
    }
    // W tile: 256 o x 64 c, f32 -> fp16, vt-layout + swizzle
#pragma unroll
    for (int p = 0; p < 8; ++p) {
      int o = p * 32 + (t >> 4), c4 = (t & 15) * 4;
      float4 wv = *(const float4*)(W + (size_t)o * CC + ks * 64 + c4);
      ushort4 pk;
      pk.x = f2h(wv.x); pk.y = f2h(wv.y); pk.z = f2h(wv.z); pk.w = f2h(wv.w);
      int ch = c4 >> 3;
      *(ushort4*)&wh[o * 64 + (((ch ^ o) & 7) << 3) + (c4 & 7)] = pk;
    }
    __syncthreads();
    // transpose-pack: xa[n][c] fp16 (A-operand layout, vt swizzle)
#pragma unroll
    for (int s = 0; s < 2; ++s) {
      int n = t >> 2, cb = (t & 3) * 16 + s * 8;
      union { unsigned short u[8]; uint4 v4; } tmp;
#pragma unroll
      for (int i = 0; i < 8; ++i) tmp.u[i] = f2h(xf[(cb + i) * 133 + n]);
      *(uint4*)&xa[n * 64 + ((((cb >> 3) ^ n) & 7) << 3)] = tmp.v4;
    }
    __syncthreads();
#pragma unroll
    for (int kc = 0; kc < 2; ++kc) {
      half8 af = *(const half8*)&xa[vt_off(w * 16 + l15, kc * 4 + quad)];
#pragma unroll
      for (int ct = 0; ct < 16; ++ct) {
        half8 bf = *(const half8*)&wh[vt_off(ct * 16 + l15, kc * 4 + quad)];
        acc[ct] = __builtin_amdgcn_mfma_f32_16x16x32_f16(af, bf, acc[ct], 0, 0, 0);
      }
    }
  }
#pragma unroll
  for (int ct = 0; ct < 16; ++ct) {
    float bv_ = bias[ct * 16 + l15];
#pragma unroll
    for (int r = 0; r < 4; ++r) acc[ct][r] += bv_;
  }
  __syncthreads();   // ps dead; reuse as epilogue staging
  if (proj < 2) {
    unsigned short (*qo)[264] = (unsigned short(*)[264])ps;  // 128 x 264 shorts
#pragma unroll
    for (int ct = 0; ct < 16; ++ct)
#pragma unroll
      for (int r = 0; r < 4; ++r)
        qo[w * 16 + quad * 4 + r][ct * 16 + l15] = f2h(acc[ct][r]);
    __syncthreads();
    unsigned short* outp = (proj == 0 ? Q : K) + ((size_t)b * NN + n0) * CC;
#pragma unroll
    for (int p = 0; p < 8; ++p) {
      int f = p * 8192 + t * 16;
      int n = f >> 9, off = f & 511;
      *(uint4*)((char*)outp + (size_t)n * 512 + off) =
        *(const uint4*)((const char*)&qo[n][0] + off);
    }
  } else {
    unsigned short (*vo)[132] = (unsigned short(*)[132])ps;  // 256 x 132 shorts
#pragma unroll
    for (int ct = 0; ct < 16; ++ct)
#pragma unroll
      for (int r = 0; r < 4; ++r)
        vo[ct * 16 + l15][w * 16 + quad * 4 + r] = f2h(acc[ct][r]);
    __syncthreads();
#pragma unroll
    for (int p = 0; p < 8; ++p) {
      int f = p * 8192 + t * 16;
      int o = f >> 8, off = f & 255;
      *(uint4*)((char*)V + (((size_t)b * CC + o) * NN + n0) * 2 + off) =
        *(const uint4*)((const char*)&vo[o][0] + off);
    }
  }
}

// ---------------- flash attention (c-split PV) ----------------
// 512 thd / 8 waves. S-phase: wave w owns q-rows [w*16, w*16+16), reads full
// K tile. PV-phase: wave w = (q-group g=w>>1 (32 q), c-half h=w&1 (128 c)),
// reading only HALF of vt — per-iter LDS reads 528 -> 416 b128. alpha / final
// l exchanged through 1 KB LDS (broadcast reads). K double-buffered; both
// DMAs issue at iter top (full-iter landing window, drained at mid-barrier).
__global__ __launch_bounds__(512) void k_flash(const unsigned short* __restrict__ Q,
    const unsigned short* __restrict__ K, const unsigned short* __restrict__ V,
    float* __restrict__ out, unsigned short* __restrict__ opart,
    float* __restrict__ ml, int n_splits) {
  __shared__ unsigned short ktA[16384], ktB[16384];  // 32KB each: 64 k x 256 c
  __shared__ unsigned short vt[16384];               // 32KB: 256 c x 64 k
  __shared__ unsigned short pt[8192];                // 16KB: 128 q x 64 k
  __shared__ float al[128], ll[128];
  int b = blockIdx.y, q0 = blockIdx.x * 128, split = blockIdx.z;
  int nper = 64 / n_splits;
  int t = threadIdx.x, w = t >> 6, lane = t & 63, l15 = lane & 15, quad = lane >> 4;
  int g = w >> 1, h = w & 1;

  half8 qf[8];
  const unsigned short* qrow = Q + ((size_t)b * NN + q0 + w * 16 + l15) * CC;
#pragma unroll
  for (int k = 0; k < 8; ++k) qf[k] = *(const half8*)(qrow + k * 32 + quad * 8);

  f32x4 z = {0.f, 0.f, 0.f, 0.f};
  f32x4 o_acc[2][8];   // [mt: 16q][ct: 16c] -> 32q x 128c per wave
#pragma unroll
  for (int mt = 0; mt < 2; ++mt)
#pragma unroll
    for (int i = 0; i < 8; ++i) o_acc[mt][i] = z;
  float m_i[4], lp_[4];
#pragma unroll
  for (int r = 0; r < 4; ++r) { m_i[r] = -INFINITY; lp_[r] = 0.f; }

  int it_beg = split * nper, it_end = it_beg + nper;

  auto dma_k = [&](int it, unsigned short* dst) {
    const char* kb = (const char*)(K + ((size_t)b * NN + it * 64) * CC);
#pragma unroll
    for (int p = 0; p < 4; ++p) {
      int c = p * 512 + t;
      int r = c >> 5, lo = c & 31;
      int ch = (lo & 24) | ((lo ^ r) & 7);
      ASYNC16(kb + r * 512 + ch * 16, &dst[(p * 512 + (w << 6)) * 8]);
    }
  };
  auto dma_v = [&](int it) {
    const char* vb = (const char*)(V + (size_t)b * CC * NN + it * 64);
#pragma unroll
    for (int p = 0; p < 4; ++p) {
      int c = p * 512 + t;
      int r = c >> 3;
      int ch = (c ^ r) & 7;
      ASYNC16(vb + (size_t)r * 8192 + ch * 16, &vt[(p * 512 + (w << 6)) * 8]);
    }
  };

  auto body = [&](const unsigned short* cur, unsigned short* nxt, int it) {
    if (it + 1 < it_end) dma_k(it + 1, nxt);
    dma_v(it);

    // S = Q K^T : 16 q x 64 keys per wave
    f32x4 sa[4];
#pragma unroll
    for (int j = 0; j < 4; ++j) sa[j] = z;
#pragma unroll
    for (int kk = 0; kk < 8; ++kk) {
#pragma unroll
      for (int j = 0; j < 4; ++j) {
        half8 bf = *(const half8*)&cur[row512_off(j * 16 + l15, kk * 4 + quad)];
        sa[j] = __builtin_amdgcn_mfma_f32_16x16x32_f16(qf[kk], bf, sa[j], 0, 0, 0);
      }
    }
    // online softmax (S-wave rows w*16 + quad*4 + r)
    float mt4[4];
#pragma unroll
    for (int r = 0; r < 4; ++r)
      mt4[r] = fmaxf(fmaxf(sa[0][r], sa[1][r]), fmaxf(sa[2][r], sa[3][r]));
#pragma unroll
    for (int off = 1; off < 16; off <<= 1)
#pragma unroll
      for (int r = 0; r < 4; ++r)
        mt4[r] = fmaxf(mt4[r], __shfl_xor(mt4[r], off, 64));
    float alpha[4];
#pragma unroll
    for (int r = 0; r < 4; ++r) {
      float mn = fmaxf(m_i[r], mt4[r]);
      alpha[r] = __expf(m_i[r] - mn);
      m_i[r] = mn;
    }
#pragma unroll
    for (int r = 0; r < 4; ++r) {
      float ls = 0.f;
#pragma unroll
      for (int j = 0; j < 4; ++j) {
        float p = __expf(sa[j][r] - m_i[r]);
        sa[j][r] = p;
        ls += p;
      }
      lp_[r] = lp_[r] * alpha[r] + ls;
    }
    if (l15 == 0) {
#pragma unroll
      for (int r = 0; r < 4; ++r) al[w * 16 + quad * 4 + r] = alpha[r];
    }
    // P -> pt (block-visible, A-operand layout, swizzled)
#pragma unroll
    for (int j = 0; j < 4; ++j)
#pragma unroll
      for (int r = 0; r < 4; ++r) {
        int row = w * 16 + quad * 4 + r;
        int ch = 2 * j + (l15 >> 3);
        pt[row * 64 + (((ch ^ row) & 7) << 3) + (l15 & 7)] = f2h(sa[j][r]);
      }
    __syncthreads();   // drains both DMAs; P + alpha visible

    // PV: wave handles q-group g (32 q) x c-half h (128 c)
    float a_al[2][4];
#pragma unroll
    for (int mt = 0; mt < 2; ++mt)
#pragma unroll
      for (int r = 0; r < 4; ++r)
        a_al[mt][r] = al[g * 32 + mt * 16 + quad * 4 + r];
#pragma unroll
    for (int mt = 0; mt < 2; ++mt)
#pragma unroll
      for (int ct = 0; ct < 8; ++ct)
#pragma unroll
        for (int r = 0; r < 4; ++r) o_acc[mt][ct][r] *= a_al[mt][r];
#pragma unroll
    for (int ks2 = 0; ks2 < 2; ++ks2) {
      half8 af[2];
#pragma unroll
      for (int mt = 0; mt < 2; ++mt) {
        int row_p = g * 32 + mt * 16 + l15;
        af[mt] = *(const half8*)&pt[row_p * 64 + ((((ks2 * 4 + quad) ^ row_p) & 7) << 3)];
      }
#pragma unroll
      for (int ct = 0; ct < 8; ++ct) {
        half8 bf = *(const half8*)&vt[vt_off(h * 128 + ct * 16 + l15, ks2 * 4 + quad)];
#pragma unroll
        for (int mt = 0; mt < 2; ++mt)
          o_acc[mt][ct] = __builtin_amdgcn_mfma_f32_16x16x32_f16(af[mt], bf, o_acc[mt][ct], 0, 0, 0);
      }
    }
    __syncthreads();   // vt / pt / al free for next iter
  };

  dma_k(it_beg, ktA);
  __syncthreads();
  for (int it = it_beg; it < it_end; it += 2) {   // nper even (64 or 32)
    body(ktA, ktB, it);
    body(ktB, ktA, it + 1);
  }

  // final l per S-row; publish for PV-waves
#pragma unroll
  for (int off = 1; off < 16; off <<= 1)
#pragma unroll
    for (int r = 0; r < 4; ++r)
      lp_[r] += __shfl_xor(lp_[r], off, 64);
  if (l15 == 0) {
#pragma unroll
    for (int r = 0; r < 4; ++r) ll[w * 16 + quad * 4 + r] = lp_[r];
  }
  if (n_splits != 1 && l15 == 0) {
    size_t qi = (size_t)q0 + w * 16 + quad * 4;
    float* mp = ml + ((size_t)(split * 2 + 0) * BB + b) * NN + qi;
    float* lq = ml + ((size_t)(split * 2 + 1) * BB + b) * NN + qi;
#pragma unroll
    for (int r = 0; r < 4; ++r) { mp[r] = m_i[r]; lq[r] = lp_[r]; }
  }
  __syncthreads();
  float sc[2][4];
#pragma unroll
  for (int mt = 0; mt < 2; ++mt)
#pragma unroll
    for (int r = 0; r < 4; ++r) {
      float lv = ll[g * 32 + mt * 16 + quad * 4 + r];
      sc[mt][r] = (n_splits == 1) ? 1.f / lv : 1.f;
    }

  // epilogue: od f32 [32 c][132 q] overlay on ktA; 8 passes of 32 c-rows
  float* od = (float*)ktA;
  float* obf = out + (size_t)b * CC * NN + q0;
  unsigned short* obh = opart + ((size_t)split * BB + b) * CC * NN + q0;
#pragma unroll
  for (int pp = 0; pp < 8; ++pp) {
    __syncthreads();
    if (h == (pp >> 2)) {   // this wave's c-half contributes
#pragma unroll
      for (int cp = 0; cp < 2; ++cp) {
        int ct = (pp & 3) * 2 + cp;
#pragma unroll
        for (int mt = 0; mt < 2; ++mt)
#pragma unroll
          for (int r = 0; r < 4; ++r)
            od[(cp * 16 + l15) * 132 + g * 32 + mt * 16 + quad * 4 + r] =
                o_acc[mt][ct][r] * sc[mt][r];
      }
    }
    __syncthreads();
    if (n_splits == 1) {
#pragma unroll
      for (int p2 = 0; p2 < 2; ++p2) {
        int row = p2 * 16 + (t >> 5);
        *(float4*)(obf + (size_t)(pp * 32 + row) * NN + (t & 31) * 4) =
          *(const float4*)&od[row * 132 + (t & 31) * 4];
      }
    } else {
      int row = t >> 4, q8 = (t & 15) * 8;
      union { unsigned short u[8]; uint4 v4; } tmp;
#pragma unroll
      for (int i2 = 0; i2 < 8; ++i2) tmp.u[i2] = f2h(od[row * 132 + q8 + i2]);
      *(uint4*)(obh + (size_t)(pp * 32 + row) * NN + q8) = tmp.v4;
    }
  }
}

// ---------------- merge of 2 key-splits ----------------
__global__ __launch_bounds__(256) void k_merge(const unsigned short* __restrict__ opart,
    const float* __restrict__ ml, float* __restrict__ out) {
  size_t i = ((size_t)blockIdx.x * 256 + threadIdx.x) * 4;
  int n = (int)(i & (NN - 1));
  int b = (int)(i >> 20);   // i / (CC*NN)
  float4 m1 = *(const float4*)(ml + ((size_t)(0 * BB) + b) * NN + n);
  float4 l1 = *(const float4*)(ml + ((size_t)(1 * BB) + b) * NN + n);
  float4 m2 = *(const float4*)(ml + ((size_t)(2 * BB) + b) * NN + n);
  float4 l2 = *(const float4*)(ml + ((size_t)(3 * BB) + b) * NN + n);
  ushort4 o1 = *(const ushort4*)(opart + i);
  ushort4 o2 = *(const ushort4*)(opart + (size_t)BB * CC * NN + i);
  float4 res;
#define MRG(f, comp) { \
    float M = fmaxf(m1.f, m2.f); \
    float e1 = __expf(m1.f - M), e2 = __expf(m2.f - M); \
    res.f = (e1 * h2f(o1.comp) + e2 * h2f(o2.comp)) / (e1 * l1.f + e2 * l2.f); }
  MRG(x, x) MRG(y, y) MRG(z, z) MRG(w, w)
#undef MRG
  *(float4*)(out + i) = res;
}

extern "C" void kernel_launch(void* const* d_in, const int* in_sizes, int n_in,
                              void* d_out, int out_size, void* d_ws, size_t ws_size,
                              hipStream_t stream) {
  const float* x  = (const float*)d_in[0];
  const float* Wq = (const float*)d_in[1];
  const float* bq = (const float*)d_in[2];
  const float* Wk = (const float*)d_in[3];
  const float* bk = (const float*)d_in[4];
  const float* Wv = (const float*)d_in[5];
  const float* bv = (const float*)d_in[6];
  float* out = (float*)d_out;
  char* ws = (char*)d_ws;
  const size_t MB = 1024 * 1024;
  unsigned short* Qb = (unsigned short*)(ws);             // 8 MB fp16 (B,N,C)
  unsigned short* Kb = (unsigned short*)(ws + 8 * MB);    // 8 MB fp16 (B,N,C)
  unsigned short* Vb = (unsigned short*)(ws + 16 * MB);   // 8 MB fp16 (B,C,N)
  unsigned short* Op = (unsigned short*)(ws + 24 * MB);   // 16 MB fp16 partials
  float*          Ml = (float*)(ws + 40 * MB);            // 256 KB

  k_proj<<<dim3(32, 4, 3), 512, 0, stream>>>(x, Wq, bq, Wk, bk, Wv, bv, Qb, Kb, Vb);

  int ns = (ws_size >= 41 * MB) ? 2 : 1;
  k_flash<<<dim3(32, 4, ns), 512, 0, stream>>>(Qb, Kb, Vb, out, Op, Ml, ns);
  if (ns == 2) k_merge<<<dim3(4096), 256, 0, stream>>>(Op, Ml, out);
}

// Round 12
// 213.202 us; speedup vs baseline: 1.2194x; 1.0089x over previous
//
#include <hip/hip_runtime.h>
#include <math.h>

#define BB 4
#define CC 256
#define NN 4096

using half8 = __attribute__((ext_vector_type(8))) _Float16;
using f32x4 = __attribute__((ext_vector_type(4))) float;

__device__ __forceinline__ unsigned short f2h(float f) {
  _Float16 h = (_Float16)f;   // RNE
  return __builtin_bit_cast(unsigned short, h);
}
__device__ __forceinline__ float h2f(unsigned short u) {
  return (float)__builtin_bit_cast(_Float16, u);
}

// async global->LDS DMA, 16B per lane; LDS dest = wave-uniform base + lane*16
#define ASYNC16(g, l)                                                        \
  __builtin_amdgcn_global_load_lds(                                          \
      (const __attribute__((address_space(1))) unsigned int*)(g),            \
      (__attribute__((address_space(3))) unsigned int*)(l), 16, 0, 0)

// XOR bank swizzle at 16B-chunk granularity
__device__ __forceinline__ int row512_off(int r, int chunk) {  // rows of 512B
  return r * 256 + (((chunk & 24) | ((chunk ^ r) & 7)) << 3);
}
__device__ __forceinline__ int vt_off(int r, int chunk) {      // rows of 128B
  return r * 64 + (((chunk ^ r) & 7) << 3);
}

// ---------------- W pre-cast + pre-tile ----------------
// Wt chunk (p3, ks, o, pos8) = W_p3[o][ks*64 + ((pos8^o)&7)*8 .. +8] as fp16.
// This is exactly the swizzled LDS image k_proj wants, so its W staging is a
// linear global_load_lds DMA.
__global__ __launch_bounds__(256) void k_wcast(const float* __restrict__ Wq,
    const float* __restrict__ Wk, const float* __restrict__ Wv,
    unsigned short* __restrict__ Wt) {
  int id = blockIdx.x * 256 + threadIdx.x;     // 24576 chunks
  int pos8 = id & 7, o = (id >> 3) & 255, ks = (id >> 11) & 3, p3 = id >> 13;
  const float* W = p3 == 0 ? Wq : (p3 == 1 ? Wk : Wv);
  int c = ks * 64 + ((pos8 ^ o) & 7) * 8;
  const float* src = W + (size_t)o * CC + c;
  float4 a = *(const float4*)(src);
  float4 b4 = *(const float4*)(src + 4);
  union { unsigned short u[8]; uint4 v4; } pk;
  pk.u[0] = f2h(a.x);  pk.u[1] = f2h(a.y);  pk.u[2] = f2h(a.z);  pk.u[3] = f2h(a.w);
  pk.u[4] = f2h(b4.x); pk.u[5] = f2h(b4.y); pk.u[6] = f2h(b4.z); pk.u[7] = f2h(b4.w);
  *(uint4*)(Wt + (size_t)id * 8) = pk.v4;
}

// ---------------- fused 3-projection kernel ----------------
// 512 thd / 8 waves; 32 n-rows per block; wave w owns o-slice [w*32, w*32+32).
// Per ks: x f32 tile -> LDS -> transpose+cast ONCE; W via linear DMA of the
// pre-tiled Wt. acc[3][2][2] = 48 VGPR fits the 512-thd 128-VGPR cap.
__global__ __launch_bounds__(512) void k_proj(const float* __restrict__ x,
    const unsigned short* __restrict__ Wt,
    const float* __restrict__ bq, const float* __restrict__ bk,
    const float* __restrict__ bv,
    unsigned short* __restrict__ Q, unsigned short* __restrict__ K,
    unsigned short* __restrict__ V) {
  __shared__ __align__(16) char ps[110848];
  float* xf = (float*)ps;                               // 64 c x 33 f32 (8448 B)
  unsigned short* xa = (unsigned short*)(ps + 8448);    // 32 n x 64 c fp16 (4096 B)
  unsigned short* wh = (unsigned short*)(ps + 12544);   // 3 x 256 o x 64 c fp16 (98304 B)
  int b = blockIdx.y, n0 = blockIdx.x * 32;
  int t = threadIdx.x, w = t >> 6, lane = t & 63, l15 = lane & 15, quad = lane >> 4;

  f32x4 z = {0.f, 0.f, 0.f, 0.f};
  f32x4 acc[3][2][2];   // [proj][ct: 16-o][mt: 16-n]
#pragma unroll
  for (int p3 = 0; p3 < 3; ++p3)
#pragma unroll
    for (int ct = 0; ct < 2; ++ct)
#pragma unroll
      for (int mt = 0; mt < 2; ++mt) acc[p3][ct][mt] = z;

  for (int ks = 0; ks < 4; ++ks) {
    if (ks) __syncthreads();   // all waves done with xa/wh of prev ks
    // W DMA: 3 projs x 32 KB, linear copy of pre-tiled Wt
#pragma unroll
    for (int p3 = 0; p3 < 3; ++p3) {
      const char* wb = (const char*)(Wt + (size_t)(p3 * 4 + ks) * 16384);
#pragma unroll
      for (int p = 0; p < 4; ++p) {
        int c = p * 512 + t;
        ASYNC16(wb + c * 16, &wh[p3 * 16384 + (p * 512 + (w << 6)) * 8]);
      }
    }
    // x f32 tile: 64 c-rows x 32 n, coalesced 16B loads
    {
      int c = t >> 3, nl = (t & 7) * 4;
      float4 v = *(const float4*)(x + ((size_t)b * CC + ks * 64 + c) * NN + n0 + nl);
      float* d = xf + c * 33 + nl;
      d[0] = v.x; d[1] = v.y; d[2] = v.z; d[3] = v.w;
    }
    __syncthreads();   // xf visible; W DMA drained
    // transpose-pack: xa[n][c] fp16 (A-layout, swizzled), once per ks
    {
      int n = t >> 4, cb = (t & 15) * 4;
      union { unsigned short u[4]; ushort4 v4; } tmp;
#pragma unroll
      for (int i = 0; i < 4; ++i) tmp.u[i] = f2h(xf[(cb + i) * 33 + n]);
      int ch = cb >> 3;
      *(ushort4*)&xa[n * 64 + (((ch ^ n) & 7) << 3) + (cb & 7)] = tmp.v4;
    }
    __syncthreads();   // xa visible
#pragma unroll
    for (int kc = 0; kc < 2; ++kc) {
      half8 af[2];
#pragma unroll
      for (int mt = 0; mt < 2; ++mt)
        af[mt] = *(const half8*)&xa[vt_off(mt * 16 + l15, kc * 4 + quad)];
#pragma unroll
      for (int p3 = 0; p3 < 3; ++p3)
#pragma unroll
        for (int ct = 0; ct < 2; ++ct) {
          half8 bf = *(const half8*)&wh[p3 * 16384 + vt_off(w * 32 + ct * 16 + l15, kc * 4 + quad)];
#pragma unroll
          for (int mt = 0; mt < 2; ++mt)
            acc[p3][ct][mt] = __builtin_amdgcn_mfma_f32_16x16x32_f16(af[mt], bf, acc[p3][ct][mt], 0, 0, 0);
        }
    }
  }
  // bias
#pragma unroll
  for (int p3 = 0; p3 < 3; ++p3) {
    const float* bias = p3 == 0 ? bq : (p3 == 1 ? bk : bv);
#pragma unroll
    for (int ct = 0; ct < 2; ++ct) {
      float bv_ = bias[w * 32 + ct * 16 + l15];
#pragma unroll
      for (int mt = 0; mt < 2; ++mt)
#pragma unroll
        for (int r = 0; r < 4; ++r) acc[p3][ct][mt][r] += bv_;
    }
  }
  // epilogues: Q, K via qo[32][264]; V via vo[256][36]
#pragma unroll
  for (int p3 = 0; p3 < 2; ++p3) {
    __syncthreads();
    unsigned short* qo = (unsigned short*)ps;   // 32 x 264
#pragma unroll
    for (int ct = 0; ct < 2; ++ct)
#pragma unroll
      for (int mt = 0; mt < 2; ++mt)
#pragma unroll
        for (int r = 0; r < 4; ++r)
          qo[(mt * 16 + quad * 4 + r) * 264 + w * 32 + ct * 16 + l15] = f2h(acc[p3][ct][mt][r]);
    __syncthreads();
    unsigned short* outp = (p3 == 0 ? Q : K) + ((size_t)b * NN + n0) * CC;
#pragma unroll
    for (int p = 0; p < 2; ++p) {
      int f = p * 8192 + t * 16;
      int n = f >> 9, off = f & 511;
      *(uint4*)((char*)outp + (size_t)n * 512 + off) =
        *(const uint4*)((const char*)&qo[n * 264] + off);
    }
  }
  {
    __syncthreads();
    unsigned short* vo = (unsigned short*)ps;   // 256 x 36
#pragma unroll
    for (int ct = 0; ct < 2; ++ct)
#pragma unroll
      for (int mt = 0; mt < 2; ++mt)
#pragma unroll
        for (int r = 0; r < 4; ++r)
          vo[(w * 32 + ct * 16 + l15) * 36 + mt * 16 + quad * 4 + r] = f2h(acc[2][ct][mt][r]);
    __syncthreads();
#pragma unroll
    for (int p = 0; p < 2; ++p) {
      int id = p * 512 + t;
      int o = id >> 2, off = (id & 3) * 16;
      *(uint4*)((char*)(V + ((size_t)b * CC + o) * NN + n0) + off) =
        *(const uint4*)((const char*)&vo[o * 36] + off);
    }
  }
}

// ---------------- flash attention (c-split PV) — unchanged from r11 ----------
__global__ __launch_bounds__(512) void k_flash(const unsigned short* __restrict__ Q,
    const unsigned short* __restrict__ K, const unsigned short* __restrict__ V,
    float* __restrict__ out, unsigned short* __restrict__ opart,
    float* __restrict__ ml, int n_splits) {
  __shared__ unsigned short ktA[16384], ktB[16384];  // 32KB each: 64 k x 256 c
  __shared__ unsigned short vt[16384];               // 32KB: 256 c x 64 k
  __shared__ unsigned short pt[8192];                // 16KB: 128 q x 64 k
  __shared__ float al[128], ll[128];
  int b = blockIdx.y, q0 = blockIdx.x * 128, split = blockIdx.z;
  int nper = 64 / n_splits;
  int t = threadIdx.x, w = t >> 6, lane = t & 63, l15 = lane & 15, quad = lane >> 4;
  int g = w >> 1, h = w & 1;

  half8 qf[8];
  const unsigned short* qrow = Q + ((size_t)b * NN + q0 + w * 16 + l15) * CC;
#pragma unroll
  for (int k = 0; k < 8; ++k) qf[k] = *(const half8*)(qrow + k * 32 + quad * 8);

  f32x4 z = {0.f, 0.f, 0.f, 0.f};
  f32x4 o_acc[2][8];   // 32 q x 128 c per wave (PV role)
#pragma unroll
  for (int mt = 0; mt < 2; ++mt)
#pragma unroll
    for (int i = 0; i < 8; ++i) o_acc[mt][i] = z;
  float m_i[4], lp_[4];
#pragma unroll
  for (int r = 0; r < 4; ++r) { m_i[r] = -INFINITY; lp_[r] = 0.f; }

  int it_beg = split * nper, it_end = it_beg + nper;

  auto dma_k = [&](int it, unsigned short* dst) {
    const char* kb = (const char*)(K + ((size_t)b * NN + it * 64) * CC);
#pragma unroll
    for (int p = 0; p < 4; ++p) {
      int c = p * 512 + t;
      int r = c >> 5, lo = c & 31;
      int ch = (lo & 24) | ((lo ^ r) & 7);
      ASYNC16(kb + r * 512 + ch * 16, &dst[(p * 512 + (w << 6)) * 8]);
    }
  };
  auto dma_v = [&](int it) {
    const char* vb = (const char*)(V + (size_t)b * CC * NN + it * 64);
#pragma unroll
    for (int p = 0; p < 4; ++p) {
      int c = p * 512 + t;
      int r = c >> 3;
      int ch = (c ^ r) & 7;
      ASYNC16(vb + (size_t)r * 8192 + ch * 16, &vt[(p * 512 + (w << 6)) * 8]);
    }
  };

  auto body = [&](const unsigned short* cur, unsigned short* nxt, int it) {
    if (it + 1 < it_end) dma_k(it + 1, nxt);
    dma_v(it);

    f32x4 sa[4];
#pragma unroll
    for (int j = 0; j < 4; ++j) sa[j] = z;
#pragma unroll
    for (int kk = 0; kk < 8; ++kk) {
#pragma unroll
      for (int j = 0; j < 4; ++j) {
        half8 bf = *(const half8*)&cur[row512_off(j * 16 + l15, kk * 4 + quad)];
        sa[j] = __builtin_amdgcn_mfma_f32_16x16x32_f16(qf[kk], bf, sa[j], 0, 0, 0);
      }
    }
    float mt4[4];
#pragma unroll
    for (int r = 0; r < 4; ++r)
      mt4[r] = fmaxf(fmaxf(sa[0][r], sa[1][r]), fmaxf(sa[2][r], sa[3][r]));
#pragma unroll
    for (int off = 1; off < 16; off <<= 1)
#pragma unroll
      for (int r = 0; r < 4; ++r)
        mt4[r] = fmaxf(mt4[r], __shfl_xor(mt4[r], off, 64));
    float alpha[4];
#pragma unroll
    for (int r = 0; r < 4; ++r) {
      float mn = fmaxf(m_i[r], mt4[r]);
      alpha[r] = __expf(m_i[r] - mn);
      m_i[r] = mn;
    }
#pragma unroll
    for (int r = 0; r < 4; ++r) {
      float ls = 0.f;
#pragma unroll
      for (int j = 0; j < 4; ++j) {
        float p = __expf(sa[j][r] - m_i[r]);
        sa[j][r] = p;
        ls += p;
      }
      lp_[r] = lp_[r] * alpha[r] + ls;
    }
    if (l15 == 0) {
#pragma unroll
      for (int r = 0; r < 4; ++r) al[w * 16 + quad * 4 + r] = alpha[r];
    }
#pragma unroll
    for (int j = 0; j < 4; ++j)
#pragma unroll
      for (int r = 0; r < 4; ++r) {
        int row = w * 16 + quad * 4 + r;
        int ch = 2 * j + (l15 >> 3);
        pt[row * 64 + (((ch ^ row) & 7) << 3) + (l15 & 7)] = f2h(sa[j][r]);
      }
    __syncthreads();   // drains both DMAs; P + alpha visible

    float a_al[2][4];
#pragma unroll
    for (int mt = 0; mt < 2; ++mt)
#pragma unroll
      for (int r = 0; r < 4; ++r)
        a_al[mt][r] = al[g * 32 + mt * 16 + quad * 4 + r];
#pragma unroll
    for (int mt = 0; mt < 2; ++mt)
#pragma unroll
      for (int ct = 0; ct < 8; ++ct)
#pragma unroll
        for (int r = 0; r < 4; ++r) o_acc[mt][ct][r] *= a_al[mt][r];
#pragma unroll
    for (int ks2 = 0; ks2 < 2; ++ks2) {
      half8 af[2];
#pragma unroll
      for (int mt = 0; mt < 2; ++mt) {
        int row_p = g * 32 + mt * 16 + l15;
        af[mt] = *(const half8*)&pt[row_p * 64 + ((((ks2 * 4 + quad) ^ row_p) & 7) << 3)];
      }
#pragma unroll
      for (int ct = 0; ct < 8; ++ct) {
        half8 bf = *(const half8*)&vt[vt_off(h * 128 + ct * 16 + l15, ks2 * 4 + quad)];
#pragma unroll
        for (int mt = 0; mt < 2; ++mt)
          o_acc[mt][ct] = __builtin_amdgcn_mfma_f32_16x16x32_f16(af[mt], bf, o_acc[mt][ct], 0, 0, 0);
      }
    }
    __syncthreads();
  };

  dma_k(it_beg, ktA);
  __syncthreads();
  for (int it = it_beg; it < it_end; it += 2) {
    body(ktA, ktB, it);
    body(ktB, ktA, it + 1);
  }

#pragma unroll
  for (int off = 1; off < 16; off <<= 1)
#pragma unroll
    for (int r = 0; r < 4; ++r)
      lp_[r] += __shfl_xor(lp_[r], off, 64);
  if (l15 == 0) {
#pragma unroll
    for (int r = 0; r < 4; ++r) ll[w * 16 + quad * 4 + r] = lp_[r];
  }
  if (n_splits != 1 && l15 == 0) {
    size_t qi = (size_t)q0 + w * 16 + quad * 4;
    float* mp = ml + ((size_t)(split * 2 + 0) * BB + b) * NN + qi;
    float* lq = ml + ((size_t)(split * 2 + 1) * BB + b) * NN + qi;
#pragma unroll
    for (int r = 0; r < 4; ++r) { mp[r] = m_i[r]; lq[r] = lp_[r]; }
  }
  __syncthreads();
  float sc[2][4];
#pragma unroll
  for (int mt = 0; mt < 2; ++mt)
#pragma unroll
    for (int r = 0; r < 4; ++r) {
      float lv = ll[g * 32 + mt * 16 + quad * 4 + r];
      sc[mt][r] = (n_splits == 1) ? 1.f / lv : 1.f;
    }

  float* od = (float*)ktA;
  float* obf = out + (size_t)b * CC * NN + q0;
  unsigned short* obh = opart + ((size_t)split * BB + b) * CC * NN + q0;
#pragma unroll
  for (int pp = 0; pp < 8; ++pp) {
    __syncthreads();
    if (h == (pp >> 2)) {
#pragma unroll
      for (int cp = 0; cp < 2; ++cp) {
        int ct = (pp & 3) * 2 + cp;
#pragma unroll
        for (int mt = 0; mt < 2; ++mt)
#pragma unroll
          for (int r = 0; r < 4; ++r)
            od[(cp * 16 + l15) * 132 + g * 32 + mt * 16 + quad * 4 + r] =
                o_acc[mt][ct][r] * sc[mt][r];
      }
    }
    __syncthreads();
    if (n_splits == 1) {
#pragma unroll
      for (int p2 = 0; p2 < 2; ++p2) {
        int row = p2 * 16 + (t >> 5);
        *(float4*)(obf + (size_t)(pp * 32 + row) * NN + (t & 31) * 4) =
          *(const float4*)&od[row * 132 + (t & 31) * 4];
      }
    } else {
      int row = t >> 4, q8 = (t & 15) * 8;
      union { unsigned short u[8]; uint4 v4; } tmp;
#pragma unroll
      for (int i2 = 0; i2 < 8; ++i2) tmp.u[i2] = f2h(od[row * 132 + q8 + i2]);
      *(uint4*)(obh + (size_t)(pp * 32 + row) * NN + q8) = tmp.v4;
    }
  }
}

// ---------------- merge of 2 key-splits ----------------
__global__ __launch_bounds__(256) void k_merge(const unsigned short* __restrict__ opart,
    const float* __restrict__ ml, float* __restrict__ out) {
  size_t i = ((size_t)blockIdx.x * 256 + threadIdx.x) * 4;
  int n = (int)(i & (NN - 1));
  int b = (int)(i >> 20);   // i / (CC*NN)
  float4 m1 = *(const float4*)(ml + ((size_t)(0 * BB) + b) * NN + n);
  float4 l1 = *(const float4*)(ml + ((size_t)(1 * BB) + b) * NN + n);
  float4 m2 = *(const float4*)(ml + ((size_t)(2 * BB) + b) * NN + n);
  float4 l2 = *(const float4*)(ml + ((size_t)(3 * BB) + b) * NN + n);
  ushort4 o1 = *(const ushort4*)(opart + i);
  ushort4 o2 = *(const ushort4*)(opart + (size_t)BB * CC * NN + i);
  float4 res;
#define MRG(f, comp) { \
    float M = fmaxf(m1.f, m2.f); \
    float e1 = __expf(m1.f - M), e2 = __expf(m2.f - M); \
    res.f = (e1 * h2f(o1.comp) + e2 * h2f(o2.comp)) / (e1 * l1.f + e2 * l2.f); }
  MRG(x, x) MRG(y, y) MRG(z, z) MRG(w, w)
#undef MRG
  *(float4*)(out + i) = res;
}

extern "C" void kernel_launch(void* const* d_in, const int* in_sizes, int n_in,
                              void* d_out, int out_size, void* d_ws, size_t ws_size,
                              hipStream_t stream) {
  const float* x  = (const float*)d_in[0];
  const float* Wq = (const float*)d_in[1];
  const float* bq = (const float*)d_in[2];
  const float* Wk = (const float*)d_in[3];
  const float* bk = (const float*)d_in[4];
  const float* Wv = (const float*)d_in[5];
  const float* bv = (const float*)d_in[6];
  float* out = (float*)d_out;
  char* ws = (char*)d_ws;
  const size_t MB = 1024 * 1024;
  unsigned short* Qb = (unsigned short*)(ws);             // 8 MB fp16 (B,N,C)
  unsigned short* Kb = (unsigned short*)(ws + 8 * MB);    // 8 MB fp16 (B,N,C)
  unsigned short* Vb = (unsigned short*)(ws + 16 * MB);   // 8 MB fp16 (B,C,N)
  unsigned short* Op = (unsigned short*)(ws + 24 * MB);   // 16 MB fp16 partials
  float*          Ml = (float*)(ws + 40 * MB);            // 256 KB

  int ns = (ws_size >= 41 * MB) ? 2 : 1;
  // Wt: 384 KB pre-tiled fp16 W. Lives after Ml when split path, else in the
  // unused Op region (ws_size is constant per harness -> deterministic).
  unsigned short* Wt = (unsigned short*)(ns == 2 ? ws + 40 * MB + 256 * 1024
                                                 : ws + 24 * MB);

  k_wcast<<<dim3(96), 256, 0, stream>>>(Wq, Wk, Wv, Wt);
  k_proj<<<dim3(128, 4), 512, 0, stream>>>(x, Wt, bq, bk, bv, Qb, Kb, Vb);

  k_flash<<<dim3(32, 4, ns), 512, 0, stream>>>(Qb, Kb, Vb, out, Op, Ml, ns);
  if (ns == 2) k_merge<<<dim3(4096), 256, 0, stream>>>(Op, Ml, out);
}